// Round 17
// baseline (742.751 us; speedup 1.0000x reference)
//
#include <hip/hip_runtime.h>
#include <hip/hip_bf16.h>
#include <math.h>

typedef __bf16 bf16;
typedef __bf16 bf16x2 __attribute__((ext_vector_type(2)));
typedef __bf16 bf16x4 __attribute__((ext_vector_type(4)));
typedef __bf16 bf16x8 __attribute__((ext_vector_type(8)));
typedef float f32x4 __attribute__((ext_vector_type(4)));

#define HS 2048
#define NH 16
#define HD 128
#define LT 512
#define LI 2048
#define LQ 2560
#define MLP_D 8192
#define SPLIT 4
#define KVS (LQ / SPLIT)  // 640 kv per split
#define KVBLK 32
#define NTILES (KVS / KVBLK)  // 20

__device__ __forceinline__ f32x4 mfma16(bf16x8 a, bf16x8 b, f32x4 c) {
  return __builtin_amdgcn_mfma_f32_16x16x32_bf16(a, b, c, 0, 0, 0);
}

// async global->LDS, 16B per lane; lds dest must be wave-uniform base (+lane*16 by HW)
__device__ __forceinline__ void gl_lds16(const bf16* g, bf16* l) {
  __builtin_amdgcn_global_load_lds((const __attribute__((address_space(1))) void*)g,
                                   (__attribute__((address_space(3))) void*)l, 16, 0, 0);
}

// ---------------- silu(vec) ----------------
__global__ void k_silu(const float* __restrict__ v, float* __restrict__ s) {
  int i = blockIdx.x * 256 + threadIdx.x;
  float x = v[i];
  s[i] = x / (1.f + expf(-x));
}

// ---------------- mod GEMV: silu(vec) @ mod_w, 2-pass (deterministic) ----------------
__global__ __launch_bounds__(256) void k_mod_partial(
    const float* __restrict__ s, const float* __restrict__ w_txt,
    const float* __restrict__ w_img, float* __restrict__ part) {
  int strm = blockIdx.x / 48;
  int n = (blockIdx.x % 48) * 256 + threadIdx.x;
  const float* w = strm ? w_img : w_txt;
  int k0 = blockIdx.y * 256;
  __shared__ float sl[256];
  sl[threadIdx.x] = s[k0 + threadIdx.x];
  __syncthreads();
  float acc = 0.f;
  for (int k = 0; k < 256; k++)
    acc += sl[k] * w[(size_t)(k0 + k) * 12288 + n];
  part[((size_t)blockIdx.y * 2 + strm) * 12288 + n] = acc;
}

__global__ __launch_bounds__(256) void k_mod_reduce(
    const float* __restrict__ part, const float* __restrict__ b_txt,
    const float* __restrict__ b_img, float* __restrict__ mod) {
  int strm = blockIdx.x / 48;
  int n = (blockIdx.x % 48) * 256 + threadIdx.x;
  float acc = strm ? b_img[n] : b_txt[n];
  for (int kc = 0; kc < 8; kc++)
    acc += part[((size_t)kc * 2 + strm) * 12288 + n];
  mod[(size_t)strm * 12288 + n] = acc;
}

// ---------------- weight transpose + fp32->bf16, both streams: src[R][C] -> dst[C][R] -------
__global__ __launch_bounds__(256) void k_transpose_cvt2(
    const float* __restrict__ s0, const float* __restrict__ s1,
    bf16* __restrict__ d0, bf16* __restrict__ d1, int R, int C) {
  const float* src = blockIdx.z ? s1 : s0;
  bf16* dst = blockIdx.z ? d1 : d0;
  __shared__ float t[64][65];
  int tx = threadIdx.x & 63, ty = threadIdx.x >> 6;
  int c0 = blockIdx.x * 64, r0 = blockIdx.y * 64;
  for (int i = 0; i < 64; i += 4)
    t[ty + i][tx] = src[(size_t)(r0 + ty + i) * C + c0 + tx];
  __syncthreads();
#pragma unroll
  for (int j = 0; j < 2; j++) {
    int c = (threadIdx.x >> 3) + j * 32;
    int gg = (threadIdx.x & 7) * 8;
    bf16x8 ov;
#pragma unroll
    for (int k = 0; k < 8; k++) ov[k] = (bf16)t[gg + k][c];
    *(bf16x8*)(dst + (size_t)(c0 + c) * R + r0 + gg) = ov;
  }
}

// ---------------- LayerNorm + modulate -> bf16 (used for LN1) ----------------
__global__ __launch_bounds__(256) void k_ln_mod(
    const float* __restrict__ x0, const float* __restrict__ x1,
    const float* __restrict__ ls0, const float* __restrict__ lb0,
    const float* __restrict__ ls1, const float* __restrict__ lb1,
    const float* __restrict__ mod0, const float* __restrict__ mod1,
    int shidx, int scidx, bf16* __restrict__ out) {
  int r = blockIdx.x;
  int strm = r >= LT;
  const float* x = strm ? (x1 + (size_t)(r - LT) * HS) : (x0 + (size_t)r * HS);
  const float* ls = strm ? ls1 : ls0;
  const float* lb = strm ? lb1 : lb0;
  const float* md = strm ? mod1 : mod0;
  const float* sh = md + (size_t)shidx * HS;
  const float* sc = md + (size_t)scidx * HS;
  int t = threadIdx.x;
  float4 a = ((const float4*)x)[t * 2];
  float4 b = ((const float4*)x)[t * 2 + 1];
  float xv[8] = {a.x, a.y, a.z, a.w, b.x, b.y, b.z, b.w};
  float sum = 0.f, sq = 0.f;
#pragma unroll
  for (int j = 0; j < 8; j++) { sum += xv[j]; sq += xv[j] * xv[j]; }
#pragma unroll
  for (int m = 32; m; m >>= 1) { sum += __shfl_xor(sum, m); sq += __shfl_xor(sq, m); }
  __shared__ float red[8];
  int lane = t & 63, wid = t >> 6;
  if (!lane) { red[wid] = sum; red[wid + 4] = sq; }
  __syncthreads();
  float ts = red[0] + red[1] + red[2] + red[3];
  float tq = red[4] + red[5] + red[6] + red[7];
  float mean = ts * (1.f / HS);
  float var = tq * (1.f / HS) - mean * mean;
  float inv = rsqrtf(var + 1e-6f);
  int c0 = t * 8;
  bf16x8 ov;
#pragma unroll
  for (int j = 0; j < 8; j++) {
    int c = c0 + j;
    float v = ((xv[j] - mean) * inv * ls[c] + lb[c]) * (1.f + sc[c]) + sh[c];
    ov[j] = (bf16)v;
  }
  *(bf16x8*)(out + (size_t)r * HS + c0) = ov;
}

// ---------------- GEMM: A[2560][K] bf16 @ BT[N][K] bf16, dual-stream weights ----------------
// DOUBLE-buffered LDS (32KB -> 5 blocks/CU) + PAIRED-ROW conflict-free layout (0-conflict,
// round 11) + round-7-proven race-free ordering: vmcnt(0) -> barrier -> stage(next,buf^1)
// -> compute(cur). All ds_reads are consumed by pre-barrier MFMAs (compiler lgkmcnt), so
// overwriting buf^1 after the barrier is safe. No XCD swizzle (natural dispatch optimal).
template <int MODE>
__global__ __launch_bounds__(256) void k_gemm(
    const bf16* __restrict__ A, int K, int N, int Ksz,
    const bf16* __restrict__ BT0, const bf16* __restrict__ BT1,
    const float* __restrict__ bias0, const float* __restrict__ bias1,
    void* __restrict__ out0, void* __restrict__ out1) {
  __shared__ bf16 As[2][128 * 32];
  __shared__ bf16 Bs[2][128 * 32];
  int tid = threadIdx.x;
  int bn = blockIdx.x, bm = blockIdx.y;
  int strm = (bm * 128) >= LT;
  int lm = bm * 128 - strm * LT;
  const bf16* BT = strm ? BT1 : BT0;
  int lane = tid & 63, wid = tid >> 6;
  int wr = wid >> 1, wc = wid & 1;
  int sc_ = (lane & 7) ^ (lane >> 3);
  int Rb = wid * 16 + 2 * (lane >> 3) + (sc_ >> 2);
  int koff = (sc_ & 3) * 8;
  const bf16* Ag = A + (size_t)(bm * 128 + Rb) * K + koff;
  const bf16* Bg = BT + (size_t)(bn * 128 + Rb) * K + koff;
  int kbeg = MODE == 4 ? blockIdx.z * Ksz : 0;
  int nk = Ksz / 32;
  auto stage = [&](int buf, int ks) {
    int k0 = kbeg + ks * 32;
    gl_lds16(Ag + k0, &As[buf][wid * 512]);
    gl_lds16(Ag + (size_t)64 * K + k0, &As[buf][2048 + wid * 512]);
    gl_lds16(Bg + k0, &Bs[buf][wid * 512]);
    gl_lds16(Bg + (size_t)64 * K + k0, &Bs[buf][2048 + wid * 512]);
  };
  f32x4 acc[4][4] = {};
  int r16 = lane & 15, g = lane >> 4;
  int Lr = r16 >> 1;
  int pf_ = (((r16 & 1) << 2) + g) ^ Lr;
  stage(0, 0);
  int cur = 0;
  for (int ks = 0; ks < nk; ks++) {
    asm volatile("s_waitcnt vmcnt(0)" ::: "memory");
    __builtin_amdgcn_s_barrier();
    asm volatile("" ::: "memory");
    if (ks + 1 < nk) stage(cur ^ 1, ks + 1);
    bf16x8 af[4], bfr[4];
#pragma unroll
    for (int m = 0; m < 4; m++)
      af[m] = *(const bf16x8*)&As[cur][(wr * 32 + m * 8 + Lr) * 64 + pf_ * 8];
#pragma unroll
    for (int n = 0; n < 4; n++)
      bfr[n] = *(const bf16x8*)&Bs[cur][(wc * 32 + n * 8 + Lr) * 64 + pf_ * 8];
#pragma unroll
    for (int m = 0; m < 4; m++)
#pragma unroll
      for (int n = 0; n < 4; n++)
        acc[m][n] = mfma16(af[m], bfr[n], acc[m][n]);
    cur ^= 1;
  }
  int col = lane & 15, rb = (lane >> 4) * 4;
  const float* bias = strm ? bias1 : bias0;
  float* part = MODE == 4 ? (float*)out0 + (size_t)blockIdx.z * LQ * N : nullptr;
#pragma unroll
  for (int m = 0; m < 4; m++) {
#pragma unroll
    for (int n = 0; n < 4; n++) {
      int gn = bn * 128 + wc * 64 + n * 16 + col;
      float bv = MODE == 4 ? 0.f : bias[gn];
#pragma unroll
      for (int r = 0; r < 4; r++) {
        int lr = wr * 64 + m * 16 + rb + r;
        float v = acc[m][n][r] + bv;
        if (MODE == 0) {
          ((bf16*)(strm ? out1 : out0))[(size_t)(lm + lr) * N + gn] = (bf16)v;
        } else if (MODE == 2) {
          // gelu_tanh == v * sigmoid(2u), u = 0.79788456*(v + 0.044715 v^3)
          float u2 = 1.5957691216057308f * (v + 0.044715f * v * v * v);
          float ge = v / (1.f + __expf(-u2));
          ((bf16*)(strm ? out1 : out0))[(size_t)(lm + lr) * N + gn] = (bf16)ge;
        } else {
          part[(size_t)(bm * 128 + lr) * N + gn] = v;
        }
      }
    }
  }
}

// ---------------- split-K combine: out = res + gate*(sum(part)+bias), f32 ----------------
template <int S>
__global__ __launch_bounds__(256) void k_skcomb(
    const float* __restrict__ part, int N,
    const float* __restrict__ bias0, const float* __restrict__ bias1,
    const float* __restrict__ gate0, const float* __restrict__ gate1,
    const float* __restrict__ res0, const float* __restrict__ res1,
    float* __restrict__ out0, float* __restrict__ out1) {
  int gid = blockIdx.x * 256 + threadIdx.x;
  int nv = N >> 2;
  int row = gid / nv, cv = gid - row * nv;
  int strm = row >= LT;
  int lrow = row - strm * LT;
  const float* bias = strm ? bias1 : bias0;
  const float* gate = strm ? gate1 : gate0;
  const float* res = strm ? res1 : res0;
  float* out = strm ? out1 : out0;
  int c = cv * 4;
  float4 acc = *(const float4*)(bias + c);
#pragma unroll
  for (int s = 0; s < S; s++) {
    float4 p = *(const float4*)(part + ((size_t)s * LQ + row) * N + c);
    acc.x += p.x; acc.y += p.y; acc.z += p.z; acc.w += p.w;
  }
  float4 g = *(const float4*)(gate + c);
  float4 r = *(const float4*)(res + (size_t)lrow * N + c);
  float4 o = {r.x + g.x * acc.x, r.y + g.y * acc.y, r.z + g.z * acc.z, r.w + g.w * acc.w};
  *(float4*)(out + (size_t)lrow * N + c) = o;
}

// ---------------- fused proj split-K combine + LN2 + modulate ----------------
__global__ __launch_bounds__(256) void k_skcomb_ln(
    const float* __restrict__ part,
    const float* __restrict__ pb0, const float* __restrict__ pb1,
    const float* __restrict__ gate0, const float* __restrict__ gate1,
    const float* __restrict__ res0, const float* __restrict__ res1,
    const float* __restrict__ ls0, const float* __restrict__ lb0,
    const float* __restrict__ ls1, const float* __restrict__ lb1,
    const float* __restrict__ mod0, const float* __restrict__ mod1,
    float* __restrict__ x2, bf16* __restrict__ xm2) {
  int r = blockIdx.x;
  int strm = r >= LT;
  int lrow = r - strm * LT;
  const float* bias = strm ? pb1 : pb0;
  const float* gate = strm ? gate1 : gate0;
  const float* res = (strm ? res1 : res0) + (size_t)lrow * HS;
  const float* ls = strm ? ls1 : ls0;
  const float* lb = strm ? lb1 : lb0;
  const float* md = strm ? mod1 : mod0;
  const float* sh = md + 3 * HS;
  const float* sc = md + 4 * HS;
  int t = threadIdx.x, c0 = t * 8;
  float vv[8];
#pragma unroll
  for (int j = 0; j < 2; j++) {
    float4 p0 = *(const float4*)(part + (size_t)r * HS + c0 + 4 * j);
    float4 p1 = *(const float4*)(part + ((size_t)LQ + r) * HS + c0 + 4 * j);
    float4 bi = *(const float4*)(bias + c0 + 4 * j);
    float4 gt = *(const float4*)(gate + c0 + 4 * j);
    float4 rs = *(const float4*)(res + c0 + 4 * j);
    float4 o;
    o.x = rs.x + gt.x * (p0.x + p1.x + bi.x);
    o.y = rs.y + gt.y * (p0.y + p1.y + bi.y);
    o.z = rs.z + gt.z * (p0.z + p1.z + bi.z);
    o.w = rs.w + gt.w * (p0.w + p1.w + bi.w);
    *(float4*)(x2 + (size_t)r * HS + c0 + 4 * j) = o;
    vv[4 * j + 0] = o.x; vv[4 * j + 1] = o.y; vv[4 * j + 2] = o.z; vv[4 * j + 3] = o.w;
  }
  float sum = 0.f, sq = 0.f;
#pragma unroll
  for (int j = 0; j < 8; j++) { sum += vv[j]; sq += vv[j] * vv[j]; }
#pragma unroll
  for (int m = 32; m; m >>= 1) { sum += __shfl_xor(sum, m); sq += __shfl_xor(sq, m); }
  __shared__ float red[8];
  int lane = t & 63, wid = t >> 6;
  if (!lane) { red[wid] = sum; red[wid + 4] = sq; }
  __syncthreads();
  float ts = red[0] + red[1] + red[2] + red[3];
  float tq = red[4] + red[5] + red[6] + red[7];
  float mean = ts * (1.f / HS);
  float var = tq * (1.f / HS) - mean * mean;
  float inv = rsqrtf(var + 1e-6f);
  bf16x8 ov;
#pragma unroll
  for (int j = 0; j < 8; j++) {
    int c = c0 + j;
    float v = ((vv[j] - mean) * inv * ls[c] + lb[c]) * (1.f + sc[c]) + sh[c];
    ov[j] = (bf16)v;
  }
  *(bf16x8*)(xm2 + (size_t)r * HS + c0) = ov;
}

// ---------------- qkv post: RMS norm (q,k) + RoPE + scale ----------------
__global__ __launch_bounds__(256) void k_qkv_post(
    const bf16* __restrict__ y, const float* __restrict__ pe,
    const float* __restrict__ qn0, const float* __restrict__ kn0,
    const float* __restrict__ qn1, const float* __restrict__ kn1,
    bf16* __restrict__ qh, bf16* __restrict__ kh) {
  int wv = (int)((blockIdx.x * 256 + threadIdx.x) >> 6);
  int lane = threadIdx.x & 63;
  int head = wv / LQ, l = wv - head * LQ;
  const bf16* yr = y + (size_t)l * (3 * HS) + head * HD;
  float q0 = (float)yr[2 * lane], q1 = (float)yr[2 * lane + 1];
  float k0 = (float)yr[HS + 2 * lane], k1 = (float)yr[HS + 2 * lane + 1];
  float sqs = q0 * q0 + q1 * q1, sks = k0 * k0 + k1 * k1;
#pragma unroll
  for (int m = 1; m < 64; m <<= 1) { sqs += __shfl_xor(sqs, m); sks += __shfl_xor(sks, m); }
  float rq = rsqrtf(sqs * (1.f / HD) + 1e-6f);
  float rk = rsqrtf(sks * (1.f / HD) + 1e-6f);
  int strm = l >= LT;
  const float* qn = strm ? qn1 : qn0;
  const float* kn = strm ? kn1 : kn0;
  float e0 = q0 * rq * qn[2 * lane], e1 = q1 * rq * qn[2 * lane + 1];
  float f0 = k0 * rk * kn[2 * lane], f1 = k1 * rk * kn[2 * lane + 1];
  float4 p = *(const float4*)(pe + ((size_t)l * 64 + lane) * 4);
  // 128^-0.5 * log2(e) folded into q: softmax runs in exp2 domain
  const float scl = 0.12751744f;
  size_t qi = ((size_t)head * LQ + l) * HD + 2 * lane;
  bf16x2 qv = {(bf16)((p.x * e0 + p.y * e1) * scl), (bf16)((p.z * e0 + p.w * e1) * scl)};
  bf16x2 kv = {(bf16)(p.x * f0 + p.y * f1), (bf16)(p.z * f0 + p.w * f1)};
  *(bf16x2*)(qh + qi) = qv;
  *(bf16x2*)(kh + qi) = kv;
}

// ---------------- V transpose: y v-part [l][head*HD+d] -> vT [head][d][l] ----------------
__global__ __launch_bounds__(256) void k_vtrans(const bf16* __restrict__ y,
                                                bf16* __restrict__ vT) {
  __shared__ bf16 t[32][34];
  int head = blockIdx.y >> 2, dt = blockIdx.y & 3;
  int tx = threadIdx.x & 31, ty = threadIdx.x >> 5;
  int l0 = blockIdx.x * 32, d0 = dt * 32;
  for (int i = 0; i < 32; i += 8)
    t[ty + i][tx] = y[(size_t)(l0 + ty + i) * (3 * HS) + 2 * HS + head * HD + d0 + tx];
  __syncthreads();
  for (int i = 0; i < 32; i += 8)
    vT[(size_t)(head * HD + d0 + ty + i) * LQ + l0 + tx] = t[tx][ty + i];
}

// ---------------- flash attention: KV-split x4, dbuf LDS, swapped-QK, 2 q-groups/wave ------
__global__ __launch_bounds__(256, 2) void k_attn(
    const bf16* __restrict__ Q, const bf16* __restrict__ Kh,
    const bf16* __restrict__ VT, bf16* __restrict__ Op, float* __restrict__ ml) {
  __shared__ bf16 Ks[2][KVBLK * 128];
  __shared__ bf16 Vs[2][128 * KVBLK];
  int tid = threadIdx.x, lane = tid & 63, w = tid >> 6;
  int b = blockIdx.x;
  int qb = b % 20;
  int split = (b / 20) % SPLIT;
  int head = b / (20 * SPLIT);
  int qr = qb * 128 + w * 32;
  int r16 = lane & 15, g = lane >> 4;
  const bf16* qpa = Q + ((size_t)head * LQ + qr + r16) * HD + g * 8;
  const bf16* qpb = qpa + (size_t)16 * HD;
  bf16x8 qfa[4], qfb[4];
#pragma unroll
  for (int c = 0; c < 4; c++) {
    qfa[c] = *(const bf16x8*)(qpa + c * 32);
    qfb[c] = *(const bf16x8*)(qpb + c * 32);
  }
  f32x4 Oa[8] = {}, Ob[8] = {};
  float mra = -1e30f, lra = 0.f, mrb = -1e30f, lrb = 0.f;
  const bf16* kbase = Kh + ((size_t)head * LQ + split * KVS) * HD;
  const bf16* vbase = VT + (size_t)head * HD * LQ + split * KVS;
  int krow0 = w * 8 + (lane >> 4);
  int kslot = lane & 15;
  int vc_ = (lane & 7) ^ (lane >> 3);
  int vd0 = w * 32 + 2 * (lane >> 3) + (vc_ >> 2);
  int vkoff = (vc_ & 3) * 8;
  auto stage = [&](int buf, int t) {
    int kv0 = t * KVBLK;
#pragma unroll
    for (int i = 0; i < 2; i++) {
      int krow = krow0 + i * 4;
      gl_lds16(kbase + (size_t)(kv0 + krow) * HD + ((kslot ^ (krow & 7)) << 3),
               &Ks[buf][(w * 8 + i * 4) * 128]);
      gl_lds16(vbase + (size_t)(vd0 + i * 16) * LQ + kv0 + vkoff,
               &Vs[buf][w * 1024 + i * 512]);
    }
  };
  stage(0, 0);
  int cur = 0;
  int src0 = r16 + ((g & 1) << 5);
  bool hiS = g >= 2;
  int LrV = r16 >> 1;
  int pv_ = (((r16 & 1) << 2) + g) ^ LrV;
  auto smpack = [&](f32x4 S0, f32x4 S1, float& mr, float& lr, float& alpha,
                    bool& keep) -> bf16x8 {
    float mx = fmaxf(fmaxf(fmaxf(S0[0], S0[1]), fmaxf(S0[2], S0[3])),
                     fmaxf(fmaxf(S1[0], S1[1]), fmaxf(S1[2], S1[3])));
    mx = fmaxf(mx, __shfl_xor(mx, 16));
    mx = fmaxf(mx, __shfl_xor(mx, 32));
    keep = __all(mx <= mr + 8.f);
    alpha = 1.f;
    if (!keep) {
      float mn = fmaxf(mr, mx);
      alpha = exp2f(mr - mn);
      mr = mn;
    }
    float p0 = exp2f(S0[0] - mr), p1 = exp2f(S0[1] - mr);
    float p2 = exp2f(S0[2] - mr), p3 = exp2f(S0[3] - mr);
    float p4 = exp2f(S1[0] - mr), p5 = exp2f(S1[1] - mr);
    float p6 = exp2f(S1[2] - mr), p7 = exp2f(S1[3] - mr);
    float rs = ((p0 + p1) + (p2 + p3)) + ((p4 + p5) + (p6 + p7));
    rs += __shfl_xor(rs, 16);
    rs += __shfl_xor(rs, 32);
    lr = fmaf(lr, alpha, rs);
    bf16x2 a0 = {(bf16)p0, (bf16)p1}, a1 = {(bf16)p2, (bf16)p3};
    bf16x2 b0 = {(bf16)p4, (bf16)p5}, b1 = {(bf16)p6, (bf16)p7};
    int A0 = *(int*)&a0, A1 = *(int*)&a1, B0 = *(int*)&b0, B1 = *(int*)&b1;
    int x0a = __shfl(A0, src0), x0b = __shfl(B0, src0);
    int x1a = __shfl(A1, src0), x1b = __shfl(B1, src0);
    int x2a = __shfl(A0, src0 + 16), x2b = __shfl(B0, src0 + 16);
    int x3a = __shfl(A1, src0 + 16), x3b = __shfl(B1, src0 + 16);
    union { int u[4]; bf16x8 v; } pu;
    pu.u[0] = hiS ? x0b : x0a;
    pu.u[1] = hiS ? x1b : x1a;
    pu.u[2] = hiS ? x2b : x2a;
    pu.u[3] = hiS ? x3b : x3a;
    return pu.v;
  };
  for (int t = 0; t < NTILES; t++) {
    __syncthreads();
    if (t + 1 < NTILES) stage(cur ^ 1, t + 1);
    const bf16* ks = &Ks[cur][0];
    const bf16* vs = &Vs[cur][0];
    f32x4 S0a = {}, S1a = {}, S0b = {}, S1b = {};
    int sw = (r16 & 7);
    __builtin_amdgcn_s_setprio(1);
#pragma unroll
    for (int c = 0; c < 4; c++) {
      int slot = ((4 * c + g) ^ sw) << 3;
      bf16x8 ka = *(const bf16x8*)&ks[r16 * 128 + slot];
      bf16x8 kb = *(const bf16x8*)&ks[(16 + r16) * 128 + slot];
      S0a = mfma16(ka, qfa[c], S0a);
      S1a = mfma16(kb, qfa[c], S1a);
      S0b = mfma16(ka, qfb[c], S0b);
      S1b = mfma16(kb, qfb[c], S1b);
    }
    __builtin_amdgcn_s_setprio(0);
    float alphaa, alphab;
    bool keepa, keepb;
    bf16x8 pfa = smpack(S0a, S1a, mra, lra, alphaa, keepa);
    bf16x8 pfb = smpack(S0b, S1b, mrb, lrb, alphab, keepb);
    if (!keepa) {
#pragma unroll
      for (int n = 0; n < 8; n++) Oa[n] *= alphaa;
    }
    if (!keepb) {
#pragma unroll
      for (int n = 0; n < 8; n++) Ob[n] *= alphab;
    }
    __builtin_amdgcn_s_setprio(1);
#pragma unroll
    for (int n = 0; n < 8; n++) {
      bf16x8 vf = *(const bf16x8*)&vs[(n * 8 + LrV) * 64 + pv_ * 8];
      Oa[n] = mfma16(vf, pfa, Oa[n]);
      Ob[n] = mfma16(vf, pfb, Ob[n]);
    }
    __builtin_amdgcn_s_setprio(0);
    cur ^= 1;
  }
  const int NL = NH * LQ;
  bf16* op = Op + (size_t)split * NL * HD;
  size_t rowa = ((size_t)head * LQ + qr + r16) * HD + 4 * g;
  size_t rowb = rowa + (size_t)16 * HD;
#pragma unroll
  for (int n = 0; n < 8; n++) {
    bf16x4 ova = {(bf16)Oa[n][0], (bf16)Oa[n][1], (bf16)Oa[n][2], (bf16)Oa[n][3]};
    bf16x4 ovb = {(bf16)Ob[n][0], (bf16)Ob[n][1], (bf16)Ob[n][2], (bf16)Ob[n][3]};
    *(bf16x4*)(op + rowa + n * 16) = ova;
    *(bf16x4*)(op + rowb + n * 16) = ovb;
  }
  if (g == 0) {
    int idxa = head * LQ + qr + r16;
    ml[(size_t)(split * 2 + 0) * NL + idxa] = mra;
    ml[(size_t)(split * 2 + 1) * NL + idxa] = lra;
    ml[(size_t)(split * 2 + 0) * NL + idxa + 16] = mrb;
    ml[(size_t)(split * 2 + 1) * NL + idxa + 16] = lrb;
  }
}

// ---------------- combine SPLIT KV-parts -> attnb [l][head*HD+d] bf16 ----------------
__global__ __launch_bounds__(256) void k_attn_combine(
    const bf16* __restrict__ Op, const float* __restrict__ ml, bf16* __restrict__ out) {
  int lane = threadIdx.x & 63, w = threadIdx.x >> 6;
  int row = blockIdx.x * 4 + w;
  int head = row / LQ, l = row - head * LQ;
  const int NL = NH * LQ;
  float ms[SPLIT], ls[SPLIT], m = -1e30f;
#pragma unroll
  for (int s = 0; s < SPLIT; s++) {
    ms[s] = ml[(size_t)(s * 2) * NL + row];
    ls[s] = ml[(size_t)(s * 2 + 1) * NL + row];
    m = fmaxf(m, ms[s]);
  }
  float wsum = 0.f, wgt[SPLIT];
#pragma unroll
  for (int s = 0; s < SPLIT; s++) { wgt[s] = exp2f(ms[s] - m); wsum += wgt[s] * ls[s]; }
  float inv = 1.f / wsum;
  size_t oi = (size_t)row * HD + 2 * lane;
  float a0 = 0.f, a1 = 0.f;
#pragma unroll
  for (int s = 0; s < SPLIT; s++) {
    bf16x2 v = *(const bf16x2*)(Op + (size_t)s * NL * HD + oi);
    a0 += wgt[s] * (float)v[0];
    a1 += wgt[s] * (float)v[1];
  }
  bf16x2 ov = {(bf16)(a0 * inv), (bf16)(a1 * inv)};
  *(bf16x2*)(out + (size_t)l * HS + head * HD + 2 * lane) = ov;
}

// ---------------- launch ----------------
extern "C" void kernel_launch(void* const* d_in, const int* in_sizes, int n_in,
                              void* d_out, int out_size, void* d_ws, size_t ws_size,
                              hipStream_t stream) {
  const float* img = (const float*)d_in[0];
  const float* txt = (const float*)d_in[1];
  const float* vec = (const float*)d_in[2];
  const float* pe = (const float*)d_in[3];
#define PARAM(i) ((const float*)d_in[i])

  char* ws = (char*)d_ws;
  size_t off = 0;
  auto alloc = [&](size_t b) { void* p = ws + off; off += (b + 255) & ~(size_t)255; return p; };
  float* silu_s = (float*)alloc((size_t)HS * 4);
  float* mpart = (float*)alloc((size_t)8 * 2 * 12288 * 4);
  float* mod = (float*)alloc((size_t)2 * 6 * HS * 4);
  bf16* qkvT0 = (bf16*)alloc((size_t)3 * HS * HS * 2);
  bf16* qkvT1 = (bf16*)alloc((size_t)3 * HS * HS * 2);
  bf16* projT0 = (bf16*)alloc((size_t)HS * HS * 2);
  bf16* projT1 = (bf16*)alloc((size_t)HS * HS * 2);
  bf16* mlp1T0 = (bf16*)alloc((size_t)MLP_D * HS * 2);
  bf16* mlp1T1 = (bf16*)alloc((size_t)MLP_D * HS * 2);
  bf16* mlp2T0 = (bf16*)alloc((size_t)HS * MLP_D * 2);
  bf16* mlp2T1 = (bf16*)alloc((size_t)HS * MLP_D * 2);
  bf16* xm = (bf16*)alloc((size_t)LQ * HS * 2);
  bf16* y = (bf16*)alloc((size_t)LQ * 3 * HS * 2);
  bf16* qh = (bf16*)alloc((size_t)NH * LQ * HD * 2);
  bf16* kh = (bf16*)alloc((size_t)NH * LQ * HD * 2);
  bf16* vT = (bf16*)alloc((size_t)NH * HD * LQ * 2);
  bf16* attnb = (bf16*)alloc((size_t)LQ * HS * 2);
  float* x2 = (float*)alloc((size_t)LQ * HS * 4);
  bf16* xm2 = (bf16*)alloc((size_t)LQ * HS * 2);
  bf16* h = (bf16*)alloc((size_t)LQ * MLP_D * 2);
  float* ml = (float*)alloc((size_t)2 * SPLIT * NH * LQ * 4);
  bf16* Op = h;                 // attn partials alias h (dead until step 9)
  float* skpart = (float*)xm;   // split-K partials: proj x2 = 42MB fits xm+y;
                                // mlp2 x4 = 84MB = xm..attnb (all dead at step 10)
  (void)ws_size; (void)in_sizes; (void)n_in; (void)out_size;

  const float* t_mod = mod;
  const float* i_mod = mod + 6 * HS;

  // 1) modulation vectors
  k_silu<<<HS / 256, 256, 0, stream>>>(vec, silu_s);
  k_mod_partial<<<dim3(96, 8), 256, 0, stream>>>(silu_s, PARAM(20), PARAM(4), mpart);
  k_mod_reduce<<<96, 256, 0, stream>>>(mpart, PARAM(21), PARAM(5), mod);

  // 2) weight transpose+cvt (both streams per launch)
  k_transpose_cvt2<<<dim3(3 * HS / 64, HS / 64, 2), 256, 0, stream>>>(
      PARAM(24), PARAM(8), qkvT0, qkvT1, HS, 3 * HS);
  k_transpose_cvt2<<<dim3(HS / 64, HS / 64, 2), 256, 0, stream>>>(
      PARAM(28), PARAM(12), projT0, projT1, HS, HS);
  k_transpose_cvt2<<<dim3(MLP_D / 64, HS / 64, 2), 256, 0, stream>>>(
      PARAM(32), PARAM(16), mlp1T0, mlp1T1, HS, MLP_D);
  k_transpose_cvt2<<<dim3(HS / 64, MLP_D / 64, 2), 256, 0, stream>>>(
      PARAM(34), PARAM(18), mlp2T0, mlp2T1, MLP_D, HS);

  // 3) LN1 + modulate
  k_ln_mod<<<LQ, 256, 0, stream>>>(txt, img, PARAM(22), PARAM(23), PARAM(6), PARAM(7),
                                   t_mod, i_mod, 0, 1, xm);

  // 4) qkv GEMM
  k_gemm<0><<<dim3(3 * HS / 128, LQ / 128), 256, 0, stream>>>(
      xm, HS, 3 * HS, HS, qkvT0, qkvT1, PARAM(25), PARAM(9), y, y + (size_t)LT * 3 * HS);

  // 5) RMS + RoPE ; V transpose
  k_qkv_post<<<NH * LQ / 4, 256, 0, stream>>>(y, pe, PARAM(26), PARAM(27), PARAM(10), PARAM(11),
                                              qh, kh);
  k_vtrans<<<dim3(LQ / 32, NH * 4), 256, 0, stream>>>(y, vT);

  // 6) attention (KV-split x4, 2 q-groups/wave) + combine
  k_attn<<<NH * SPLIT * 20, 256, 0, stream>>>(qh, kh, vT, Op, ml);
  k_attn_combine<<<NH * LQ / 4, 256, 0, stream>>>(Op, ml, attnb);

  // 7) proj GEMM split-K x2 + fused combine+LN2 -> x2, xm2
  k_gemm<4><<<dim3(HS / 128, LQ / 128, 2), 256, 0, stream>>>(
      attnb, HS, HS, HS / 2, projT0, projT1, nullptr, nullptr, skpart, nullptr);
  k_skcomb_ln<<<LQ, 256, 0, stream>>>(
      skpart, PARAM(29), PARAM(13), t_mod + 2 * HS, i_mod + 2 * HS, txt, img,
      PARAM(30), PARAM(31), PARAM(14), PARAM(15), t_mod, i_mod, x2, xm2);

  // 9) MLP1 + gelu
  k_gemm<2><<<dim3(MLP_D / 128, LQ / 128), 256, 0, stream>>>(
      xm2, HS, MLP_D, HS, mlp1T0, mlp1T1, PARAM(33), PARAM(17), h, h + (size_t)LT * MLP_D);

  // 10) MLP2 split-K x4 + combine -> d_out (img first)
  float* out_img = (float*)d_out;
  float* out_txt = (float*)d_out + (size_t)LI * HS;
  k_gemm<4><<<dim3(HS / 128, LQ / 128, 4), 256, 0, stream>>>(
      h, MLP_D, HS, MLP_D / 4, mlp2T0, mlp2T1, nullptr, nullptr, skpart, nullptr);
  k_skcomb<4><<<LQ * HS / 4 / 256, 256, 0, stream>>>(
      skpart, HS, PARAM(35), PARAM(19), t_mod + 5 * HS, i_mod + 5 * HS, x2,
      x2 + (size_t)LT * HS, out_txt, out_img);
}

// Round 18
// 729.606 us; speedup vs baseline: 1.0180x; 1.0180x over previous
//
#include <hip/hip_runtime.h>
#include <hip/hip_bf16.h>
#include <math.h>

typedef __bf16 bf16;
typedef __bf16 bf16x2 __attribute__((ext_vector_type(2)));
typedef __bf16 bf16x4 __attribute__((ext_vector_type(4)));
typedef __bf16 bf16x8 __attribute__((ext_vector_type(8)));
typedef float f32x4 __attribute__((ext_vector_type(4)));

#define HS 2048
#define NH 16
#define HD 128
#define LT 512
#define LI 2048
#define LQ 2560
#define MLP_D 8192
#define SPLIT 4
#define KVS (LQ / SPLIT)  // 640 kv per split
#define KVBLK 32
#define NTILES (KVS / KVBLK)  // 20

__device__ __forceinline__ f32x4 mfma16(bf16x8 a, bf16x8 b, f32x4 c) {
  return __builtin_amdgcn_mfma_f32_16x16x32_bf16(a, b, c, 0, 0, 0);
}

// async global->LDS, 16B per lane; lds dest must be wave-uniform base (+lane*16 by HW)
__device__ __forceinline__ void gl_lds16(const bf16* g, bf16* l) {
  __builtin_amdgcn_global_load_lds((const __attribute__((address_space(1))) void*)g,
                                   (__attribute__((address_space(3))) void*)l, 16, 0, 0);
}

// ---------------- silu(vec) ----------------
__global__ void k_silu(const float* __restrict__ v, float* __restrict__ s) {
  int i = blockIdx.x * 256 + threadIdx.x;
  float x = v[i];
  s[i] = x / (1.f + expf(-x));
}

// ---------------- mod GEMV: silu(vec) @ mod_w, 2-pass (deterministic) ----------------
__global__ __launch_bounds__(256) void k_mod_partial(
    const float* __restrict__ s, const float* __restrict__ w_txt,
    const float* __restrict__ w_img, float* __restrict__ part) {
  int strm = blockIdx.x / 48;
  int n = (blockIdx.x % 48) * 256 + threadIdx.x;
  const float* w = strm ? w_img : w_txt;
  int k0 = blockIdx.y * 256;
  __shared__ float sl[256];
  sl[threadIdx.x] = s[k0 + threadIdx.x];
  __syncthreads();
  float acc = 0.f;
  for (int k = 0; k < 256; k++)
    acc += sl[k] * w[(size_t)(k0 + k) * 12288 + n];
  part[((size_t)blockIdx.y * 2 + strm) * 12288 + n] = acc;
}

__global__ __launch_bounds__(256) void k_mod_reduce(
    const float* __restrict__ part, const float* __restrict__ b_txt,
    const float* __restrict__ b_img, float* __restrict__ mod) {
  int strm = blockIdx.x / 48;
  int n = (blockIdx.x % 48) * 256 + threadIdx.x;
  float acc = strm ? b_img[n] : b_txt[n];
  for (int kc = 0; kc < 8; kc++)
    acc += part[((size_t)kc * 2 + strm) * 12288 + n];
  mod[(size_t)strm * 12288 + n] = acc;
}

// ---------------- weight transpose + fp32->bf16, both streams: src[R][C] -> dst[C][R] -------
__global__ __launch_bounds__(256) void k_transpose_cvt2(
    const float* __restrict__ s0, const float* __restrict__ s1,
    bf16* __restrict__ d0, bf16* __restrict__ d1, int R, int C) {
  const float* src = blockIdx.z ? s1 : s0;
  bf16* dst = blockIdx.z ? d1 : d0;
  __shared__ float t[64][65];
  int tx = threadIdx.x & 63, ty = threadIdx.x >> 6;
  int c0 = blockIdx.x * 64, r0 = blockIdx.y * 64;
  for (int i = 0; i < 64; i += 4)
    t[ty + i][tx] = src[(size_t)(r0 + ty + i) * C + c0 + tx];
  __syncthreads();
#pragma unroll
  for (int j = 0; j < 2; j++) {
    int c = (threadIdx.x >> 3) + j * 32;
    int gg = (threadIdx.x & 7) * 8;
    bf16x8 ov;
#pragma unroll
    for (int k = 0; k < 8; k++) ov[k] = (bf16)t[gg + k][c];
    *(bf16x8*)(dst + (size_t)(c0 + c) * R + r0 + gg) = ov;
  }
}

// ---------------- LayerNorm + modulate -> bf16 (used for LN1) ----------------
__global__ __launch_bounds__(256) void k_ln_mod(
    const float* __restrict__ x0, const float* __restrict__ x1,
    const float* __restrict__ ls0, const float* __restrict__ lb0,
    const float* __restrict__ ls1, const float* __restrict__ lb1,
    const float* __restrict__ mod0, const float* __restrict__ mod1,
    int shidx, int scidx, bf16* __restrict__ out) {
  int r = blockIdx.x;
  int strm = r >= LT;
  const float* x = strm ? (x1 + (size_t)(r - LT) * HS) : (x0 + (size_t)r * HS);
  const float* ls = strm ? ls1 : ls0;
  const float* lb = strm ? lb1 : lb0;
  const float* md = strm ? mod1 : mod0;
  const float* sh = md + (size_t)shidx * HS;
  const float* sc = md + (size_t)scidx * HS;
  int t = threadIdx.x;
  float4 a = ((const float4*)x)[t * 2];
  float4 b = ((const float4*)x)[t * 2 + 1];
  float xv[8] = {a.x, a.y, a.z, a.w, b.x, b.y, b.z, b.w};
  float sum = 0.f, sq = 0.f;
#pragma unroll
  for (int j = 0; j < 8; j++) { sum += xv[j]; sq += xv[j] * xv[j]; }
#pragma unroll
  for (int m = 32; m; m >>= 1) { sum += __shfl_xor(sum, m); sq += __shfl_xor(sq, m); }
  __shared__ float red[8];
  int lane = t & 63, wid = t >> 6;
  if (!lane) { red[wid] = sum; red[wid + 4] = sq; }
  __syncthreads();
  float ts = red[0] + red[1] + red[2] + red[3];
  float tq = red[4] + red[5] + red[6] + red[7];
  float mean = ts * (1.f / HS);
  float var = tq * (1.f / HS) - mean * mean;
  float inv = rsqrtf(var + 1e-6f);
  int c0 = t * 8;
  bf16x8 ov;
#pragma unroll
  for (int j = 0; j < 8; j++) {
    int c = c0 + j;
    float v = ((xv[j] - mean) * inv * ls[c] + lb[c]) * (1.f + sc[c]) + sh[c];
    ov[j] = (bf16)v;
  }
  *(bf16x8*)(out + (size_t)r * HS + c0) = ov;
}

// ---------------- GEMM: A[2560][K] bf16 @ BT[N][K] bf16, dual-stream weights ----------------
// DOUBLE-buffered LDS (32KB) + PAIRED-ROW conflict-free layout (0-conflict, round 11) +
// race-free ordering: vmcnt(0) -> barrier -> stage(next,buf^1) -> compute(cur).
// No XCD swizzle (natural x-fastest dispatch is the measured locality optimum).
template <int MODE>
__global__ __launch_bounds__(256) void k_gemm(
    const bf16* __restrict__ A, int K, int N, int Ksz,
    const bf16* __restrict__ BT0, const bf16* __restrict__ BT1,
    const float* __restrict__ bias0, const float* __restrict__ bias1,
    void* __restrict__ out0, void* __restrict__ out1) {
  __shared__ bf16 As[2][128 * 32];
  __shared__ bf16 Bs[2][128 * 32];
  int tid = threadIdx.x;
  int bn = blockIdx.x, bm = blockIdx.y;
  int strm = (bm * 128) >= LT;
  int lm = bm * 128 - strm * LT;
  const bf16* BT = strm ? BT1 : BT0;
  int lane = tid & 63, wid = tid >> 6;
  int wr = wid >> 1, wc = wid & 1;
  int sc_ = (lane & 7) ^ (lane >> 3);
  int Rb = wid * 16 + 2 * (lane >> 3) + (sc_ >> 2);
  int koff = (sc_ & 3) * 8;
  const bf16* Ag = A + (size_t)(bm * 128 + Rb) * K + koff;
  const bf16* Bg = BT + (size_t)(bn * 128 + Rb) * K + koff;
  int kbeg = MODE == 4 ? blockIdx.z * Ksz : 0;
  int nk = Ksz / 32;
  auto stage = [&](int buf, int ks) {
    int k0 = kbeg + ks * 32;
    gl_lds16(Ag + k0, &As[buf][wid * 512]);
    gl_lds16(Ag + (size_t)64 * K + k0, &As[buf][2048 + wid * 512]);
    gl_lds16(Bg + k0, &Bs[buf][wid * 512]);
    gl_lds16(Bg + (size_t)64 * K + k0, &Bs[buf][2048 + wid * 512]);
  };
  f32x4 acc[4][4] = {};
  int r16 = lane & 15, g = lane >> 4;
  int Lr = r16 >> 1;
  int pf_ = (((r16 & 1) << 2) + g) ^ Lr;
  stage(0, 0);
  int cur = 0;
  for (int ks = 0; ks < nk; ks++) {
    asm volatile("s_waitcnt vmcnt(0)" ::: "memory");
    __builtin_amdgcn_s_barrier();
    asm volatile("" ::: "memory");
    if (ks + 1 < nk) stage(cur ^ 1, ks + 1);
    bf16x8 af[4], bfr[4];
#pragma unroll
    for (int m = 0; m < 4; m++)
      af[m] = *(const bf16x8*)&As[cur][(wr * 32 + m * 8 + Lr) * 64 + pf_ * 8];
#pragma unroll
    for (int n = 0; n < 4; n++)
      bfr[n] = *(const bf16x8*)&Bs[cur][(wc * 32 + n * 8 + Lr) * 64 + pf_ * 8];
#pragma unroll
    for (int m = 0; m < 4; m++)
#pragma unroll
      for (int n = 0; n < 4; n++)
        acc[m][n] = mfma16(af[m], bfr[n], acc[m][n]);
    cur ^= 1;
  }
  int col = lane & 15, rb = (lane >> 4) * 4;
  const float* bias = strm ? bias1 : bias0;
  float* part = MODE == 4 ? (float*)out0 + (size_t)blockIdx.z * LQ * N : nullptr;
#pragma unroll
  for (int m = 0; m < 4; m++) {
#pragma unroll
    for (int n = 0; n < 4; n++) {
      int gn = bn * 128 + wc * 64 + n * 16 + col;
      float bv = MODE == 4 ? 0.f : bias[gn];
#pragma unroll
      for (int r = 0; r < 4; r++) {
        int lr = wr * 64 + m * 16 + rb + r;
        float v = acc[m][n][r] + bv;
        if (MODE == 0) {
          ((bf16*)(strm ? out1 : out0))[(size_t)(lm + lr) * N + gn] = (bf16)v;
        } else if (MODE == 2) {
          // gelu_tanh == v * sigmoid(2u), u = 0.79788456*(v + 0.044715 v^3)
          float u2 = 1.5957691216057308f * (v + 0.044715f * v * v * v);
          float ge = v / (1.f + __expf(-u2));
          ((bf16*)(strm ? out1 : out0))[(size_t)(lm + lr) * N + gn] = (bf16)ge;
        } else {
          part[(size_t)(bm * 128 + lr) * N + gn] = v;
        }
      }
    }
  }
}

// ---------------- split-K combine: out = res + gate*(sum(part)+bias), f32 ----------------
template <int S>
__global__ __launch_bounds__(256) void k_skcomb(
    const float* __restrict__ part, int N,
    const float* __restrict__ bias0, const float* __restrict__ bias1,
    const float* __restrict__ gate0, const float* __restrict__ gate1,
    const float* __restrict__ res0, const float* __restrict__ res1,
    float* __restrict__ out0, float* __restrict__ out1) {
  int gid = blockIdx.x * 256 + threadIdx.x;
  int nv = N >> 2;
  int row = gid / nv, cv = gid - row * nv;
  int strm = row >= LT;
  int lrow = row - strm * LT;
  const float* bias = strm ? bias1 : bias0;
  const float* gate = strm ? gate1 : gate0;
  const float* res = strm ? res1 : res0;
  float* out = strm ? out1 : out0;
  int c = cv * 4;
  float4 acc = *(const float4*)(bias + c);
#pragma unroll
  for (int s = 0; s < S; s++) {
    float4 p = *(const float4*)(part + ((size_t)s * LQ + row) * N + c);
    acc.x += p.x; acc.y += p.y; acc.z += p.z; acc.w += p.w;
  }
  float4 g = *(const float4*)(gate + c);
  float4 r = *(const float4*)(res + (size_t)lrow * N + c);
  float4 o = {r.x + g.x * acc.x, r.y + g.y * acc.y, r.z + g.z * acc.z, r.w + g.w * acc.w};
  *(float4*)(out + (size_t)lrow * N + c) = o;
}

// ---------------- fused proj split-K combine + LN2 + modulate ----------------
__global__ __launch_bounds__(256) void k_skcomb_ln(
    const float* __restrict__ part,
    const float* __restrict__ pb0, const float* __restrict__ pb1,
    const float* __restrict__ gate0, const float* __restrict__ gate1,
    const float* __restrict__ res0, const float* __restrict__ res1,
    const float* __restrict__ ls0, const float* __restrict__ lb0,
    const float* __restrict__ ls1, const float* __restrict__ lb1,
    const float* __restrict__ mod0, const float* __restrict__ mod1,
    float* __restrict__ x2, bf16* __restrict__ xm2) {
  int r = blockIdx.x;
  int strm = r >= LT;
  int lrow = r - strm * LT;
  const float* bias = strm ? pb1 : pb0;
  const float* gate = strm ? gate1 : gate0;
  const float* res = (strm ? res1 : res0) + (size_t)lrow * HS;
  const float* ls = strm ? ls1 : ls0;
  const float* lb = strm ? lb1 : lb0;
  const float* md = strm ? mod1 : mod0;
  const float* sh = md + 3 * HS;
  const float* sc = md + 4 * HS;
  int t = threadIdx.x, c0 = t * 8;
  float vv[8];
#pragma unroll
  for (int j = 0; j < 2; j++) {
    float4 p0 = *(const float4*)(part + (size_t)r * HS + c0 + 4 * j);
    float4 p1 = *(const float4*)(part + ((size_t)LQ + r) * HS + c0 + 4 * j);
    float4 bi = *(const float4*)(bias + c0 + 4 * j);
    float4 gt = *(const float4*)(gate + c0 + 4 * j);
    float4 rs = *(const float4*)(res + c0 + 4 * j);
    float4 o;
    o.x = rs.x + gt.x * (p0.x + p1.x + bi.x);
    o.y = rs.y + gt.y * (p0.y + p1.y + bi.y);
    o.z = rs.z + gt.z * (p0.z + p1.z + bi.z);
    o.w = rs.w + gt.w * (p0.w + p1.w + bi.w);
    *(float4*)(x2 + (size_t)r * HS + c0 + 4 * j) = o;
    vv[4 * j + 0] = o.x; vv[4 * j + 1] = o.y; vv[4 * j + 2] = o.z; vv[4 * j + 3] = o.w;
  }
  float sum = 0.f, sq = 0.f;
#pragma unroll
  for (int j = 0; j < 8; j++) { sum += vv[j]; sq += vv[j] * vv[j]; }
#pragma unroll
  for (int m = 32; m; m >>= 1) { sum += __shfl_xor(sum, m); sq += __shfl_xor(sq, m); }
  __shared__ float red[8];
  int lane = t & 63, wid = t >> 6;
  if (!lane) { red[wid] = sum; red[wid + 4] = sq; }
  __syncthreads();
  float ts = red[0] + red[1] + red[2] + red[3];
  float tq = red[4] + red[5] + red[6] + red[7];
  float mean = ts * (1.f / HS);
  float var = tq * (1.f / HS) - mean * mean;
  float inv = rsqrtf(var + 1e-6f);
  bf16x8 ov;
#pragma unroll
  for (int j = 0; j < 8; j++) {
    int c = c0 + j;
    float v = ((vv[j] - mean) * inv * ls[c] + lb[c]) * (1.f + sc[c]) + sh[c];
    ov[j] = (bf16)v;
  }
  *(bf16x8*)(xm2 + (size_t)r * HS + c0) = ov;
}

// ---------------- qkv post: RMS norm (q,k) + RoPE + scale ----------------
__global__ __launch_bounds__(256) void k_qkv_post(
    const bf16* __restrict__ y, const float* __restrict__ pe,
    const float* __restrict__ qn0, const float* __restrict__ kn0,
    const float* __restrict__ qn1, const float* __restrict__ kn1,
    bf16* __restrict__ qh, bf16* __restrict__ kh) {
  int wv = (int)((blockIdx.x * 256 + threadIdx.x) >> 6);
  int lane = threadIdx.x & 63;
  int head = wv / LQ, l = wv - head * LQ;
  const bf16* yr = y + (size_t)l * (3 * HS) + head * HD;
  float q0 = (float)yr[2 * lane], q1 = (float)yr[2 * lane + 1];
  float k0 = (float)yr[HS + 2 * lane], k1 = (float)yr[HS + 2 * lane + 1];
  float sqs = q0 * q0 + q1 * q1, sks = k0 * k0 + k1 * k1;
#pragma unroll
  for (int m = 1; m < 64; m <<= 1) { sqs += __shfl_xor(sqs, m); sks += __shfl_xor(sks, m); }
  float rq = rsqrtf(sqs * (1.f / HD) + 1e-6f);
  float rk = rsqrtf(sks * (1.f / HD) + 1e-6f);
  int strm = l >= LT;
  const float* qn = strm ? qn1 : qn0;
  const float* kn = strm ? kn1 : kn0;
  float e0 = q0 * rq * qn[2 * lane], e1 = q1 * rq * qn[2 * lane + 1];
  float f0 = k0 * rk * kn[2 * lane], f1 = k1 * rk * kn[2 * lane + 1];
  float4 p = *(const float4*)(pe + ((size_t)l * 64 + lane) * 4);
  // 128^-0.5 * log2(e) folded into q: softmax runs in exp2 domain
  const float scl = 0.12751744f;
  size_t qi = ((size_t)head * LQ + l) * HD + 2 * lane;
  bf16x2 qv = {(bf16)((p.x * e0 + p.y * e1) * scl), (bf16)((p.z * e0 + p.w * e1) * scl)};
  bf16x2 kv = {(bf16)(p.x * f0 + p.y * f1), (bf16)(p.z * f0 + p.w * f1)};
  *(bf16x2*)(qh + qi) = qv;
  *(bf16x2*)(kh + qi) = kv;
}

// ---------------- V transpose: y v-part [l][head*HD+d] -> vT [head][d][l] ----------------
__global__ __launch_bounds__(256) void k_vtrans(const bf16* __restrict__ y,
                                                bf16* __restrict__ vT) {
  __shared__ bf16 t[32][34];
  int head = blockIdx.y >> 2, dt = blockIdx.y & 3;
  int tx = threadIdx.x & 31, ty = threadIdx.x >> 5;
  int l0 = blockIdx.x * 32, d0 = dt * 32;
  for (int i = 0; i < 32; i += 8)
    t[ty + i][tx] = y[(size_t)(l0 + ty + i) * (3 * HS) + 2 * HS + head * HD + d0 + tx];
  __syncthreads();
  for (int i = 0; i < 32; i += 8)
    vT[(size_t)(head * HD + d0 + ty + i) * LQ + l0 + tx] = t[tx][ty + i];
}

// ---------------- flash attention: KV-split x4, dbuf LDS, swapped-QK, 2 q-groups/wave ------
__global__ __launch_bounds__(256, 2) void k_attn(
    const bf16* __restrict__ Q, const bf16* __restrict__ Kh,
    const bf16* __restrict__ VT, bf16* __restrict__ Op, float* __restrict__ ml) {
  __shared__ bf16 Ks[2][KVBLK * 128];
  __shared__ bf16 Vs[2][128 * KVBLK];
  int tid = threadIdx.x, lane = tid & 63, w = tid >> 6;
  int b = blockIdx.x;
  int qb = b % 20;
  int split = (b / 20) % SPLIT;
  int head = b / (20 * SPLIT);
  int qr = qb * 128 + w * 32;
  int r16 = lane & 15, g = lane >> 4;
  const bf16* qpa = Q + ((size_t)head * LQ + qr + r16) * HD + g * 8;
  const bf16* qpb = qpa + (size_t)16 * HD;
  bf16x8 qfa[4], qfb[4];
#pragma unroll
  for (int c = 0; c < 4; c++) {
    qfa[c] = *(const bf16x8*)(qpa + c * 32);
    qfb[c] = *(const bf16x8*)(qpb + c * 32);
  }
  f32x4 Oa[8] = {}, Ob[8] = {};
  float mra = -1e30f, lra = 0.f, mrb = -1e30f, lrb = 0.f;
  const bf16* kbase = Kh + ((size_t)head * LQ + split * KVS) * HD;
  const bf16* vbase = VT + (size_t)head * HD * LQ + split * KVS;
  int krow0 = w * 8 + (lane >> 4);
  int kslot = lane & 15;
  int vc_ = (lane & 7) ^ (lane >> 3);
  int vd0 = w * 32 + 2 * (lane >> 3) + (vc_ >> 2);
  int vkoff = (vc_ & 3) * 8;
  auto stage = [&](int buf, int t) {
    int kv0 = t * KVBLK;
#pragma unroll
    for (int i = 0; i < 2; i++) {
      int krow = krow0 + i * 4;
      gl_lds16(kbase + (size_t)(kv0 + krow) * HD + ((kslot ^ (krow & 7)) << 3),
               &Ks[buf][(w * 8 + i * 4) * 128]);
      gl_lds16(vbase + (size_t)(vd0 + i * 16) * LQ + kv0 + vkoff,
               &Vs[buf][w * 1024 + i * 512]);
    }
  };
  stage(0, 0);
  int cur = 0;
  int src0 = r16 + ((g & 1) << 5);
  bool hiS = g >= 2;
  int LrV = r16 >> 1;
  int pv_ = (((r16 & 1) << 2) + g) ^ LrV;
  auto smpack = [&](f32x4 S0, f32x4 S1, float& mr, float& lr, float& alpha,
                    bool& keep) -> bf16x8 {
    float mx = fmaxf(fmaxf(fmaxf(S0[0], S0[1]), fmaxf(S0[2], S0[3])),
                     fmaxf(fmaxf(S1[0], S1[1]), fmaxf(S1[2], S1[3])));
    mx = fmaxf(mx, __shfl_xor(mx, 16));
    mx = fmaxf(mx, __shfl_xor(mx, 32));
    keep = __all(mx <= mr + 8.f);
    alpha = 1.f;
    if (!keep) {
      float mn = fmaxf(mr, mx);
      alpha = exp2f(mr - mn);
      mr = mn;
    }
    float p0 = exp2f(S0[0] - mr), p1 = exp2f(S0[1] - mr);
    float p2 = exp2f(S0[2] - mr), p3 = exp2f(S0[3] - mr);
    float p4 = exp2f(S1[0] - mr), p5 = exp2f(S1[1] - mr);
    float p6 = exp2f(S1[2] - mr), p7 = exp2f(S1[3] - mr);
    float rs = ((p0 + p1) + (p2 + p3)) + ((p4 + p5) + (p6 + p7));
    rs += __shfl_xor(rs, 16);
    rs += __shfl_xor(rs, 32);
    lr = fmaf(lr, alpha, rs);
    bf16x2 a0 = {(bf16)p0, (bf16)p1}, a1 = {(bf16)p2, (bf16)p3};
    bf16x2 b0 = {(bf16)p4, (bf16)p5}, b1 = {(bf16)p6, (bf16)p7};
    int A0 = *(int*)&a0, A1 = *(int*)&a1, B0 = *(int*)&b0, B1 = *(int*)&b1;
    int x0a = __shfl(A0, src0), x0b = __shfl(B0, src0);
    int x1a = __shfl(A1, src0), x1b = __shfl(B1, src0);
    int x2a = __shfl(A0, src0 + 16), x2b = __shfl(B0, src0 + 16);
    int x3a = __shfl(A1, src0 + 16), x3b = __shfl(B1, src0 + 16);
    union { int u[4]; bf16x8 v; } pu;
    pu.u[0] = hiS ? x0b : x0a;
    pu.u[1] = hiS ? x1b : x1a;
    pu.u[2] = hiS ? x2b : x2a;
    pu.u[3] = hiS ? x3b : x3a;
    return pu.v;
  };
  for (int t = 0; t < NTILES; t++) {
    __syncthreads();
    if (t + 1 < NTILES) stage(cur ^ 1, t + 1);
    const bf16* ks = &Ks[cur][0];
    const bf16* vs = &Vs[cur][0];
    f32x4 S0a = {}, S1a = {}, S0b = {}, S1b = {};
    int sw = (r16 & 7);
    __builtin_amdgcn_s_setprio(1);
#pragma unroll
    for (int c = 0; c < 4; c++) {
      int slot = ((4 * c + g) ^ sw) << 3;
      bf16x8 ka = *(const bf16x8*)&ks[r16 * 128 + slot];
      bf16x8 kb = *(const bf16x8*)&ks[(16 + r16) * 128 + slot];
      S0a = mfma16(ka, qfa[c], S0a);
      S1a = mfma16(kb, qfa[c], S1a);
      S0b = mfma16(ka, qfb[c], S0b);
      S1b = mfma16(kb, qfb[c], S1b);
    }
    __builtin_amdgcn_s_setprio(0);
    float alphaa, alphab;
    bool keepa, keepb;
    bf16x8 pfa = smpack(S0a, S1a, mra, lra, alphaa, keepa);
    bf16x8 pfb = smpack(S0b, S1b, mrb, lrb, alphab, keepb);
    if (!keepa) {
#pragma unroll
      for (int n = 0; n < 8; n++) Oa[n] *= alphaa;
    }
    if (!keepb) {
#pragma unroll
      for (int n = 0; n < 8; n++) Ob[n] *= alphab;
    }
    __builtin_amdgcn_s_setprio(1);
#pragma unroll
    for (int n = 0; n < 8; n++) {
      bf16x8 vf = *(const bf16x8*)&vs[(n * 8 + LrV) * 64 + pv_ * 8];
      Oa[n] = mfma16(vf, pfa, Oa[n]);
      Ob[n] = mfma16(vf, pfb, Ob[n]);
    }
    __builtin_amdgcn_s_setprio(0);
    cur ^= 1;
  }
  const int NL = NH * LQ;
  bf16* op = Op + (size_t)split * NL * HD;
  size_t rowa = ((size_t)head * LQ + qr + r16) * HD + 4 * g;
  size_t rowb = rowa + (size_t)16 * HD;
#pragma unroll
  for (int n = 0; n < 8; n++) {
    bf16x4 ova = {(bf16)Oa[n][0], (bf16)Oa[n][1], (bf16)Oa[n][2], (bf16)Oa[n][3]};
    bf16x4 ovb = {(bf16)Ob[n][0], (bf16)Ob[n][1], (bf16)Ob[n][2], (bf16)Ob[n][3]};
    *(bf16x4*)(op + rowa + n * 16) = ova;
    *(bf16x4*)(op + rowb + n * 16) = ovb;
  }
  if (g == 0) {
    int idxa = head * LQ + qr + r16;
    ml[(size_t)(split * 2 + 0) * NL + idxa] = mra;
    ml[(size_t)(split * 2 + 1) * NL + idxa] = lra;
    ml[(size_t)(split * 2 + 0) * NL + idxa + 16] = mrb;
    ml[(size_t)(split * 2 + 1) * NL + idxa + 16] = lrb;
  }
}

// ---------------- combine SPLIT KV-parts -> attnb [l][head*HD+d] bf16 ----------------
__global__ __launch_bounds__(256) void k_attn_combine(
    const bf16* __restrict__ Op, const float* __restrict__ ml, bf16* __restrict__ out) {
  int lane = threadIdx.x & 63, w = threadIdx.x >> 6;
  int row = blockIdx.x * 4 + w;
  int head = row / LQ, l = row - head * LQ;
  const int NL = NH * LQ;
  float ms[SPLIT], ls[SPLIT], m = -1e30f;
#pragma unroll
  for (int s = 0; s < SPLIT; s++) {
    ms[s] = ml[(size_t)(s * 2) * NL + row];
    ls[s] = ml[(size_t)(s * 2 + 1) * NL + row];
    m = fmaxf(m, ms[s]);
  }
  float wsum = 0.f, wgt[SPLIT];
#pragma unroll
  for (int s = 0; s < SPLIT; s++) { wgt[s] = exp2f(ms[s] - m); wsum += wgt[s] * ls[s]; }
  float inv = 1.f / wsum;
  size_t oi = (size_t)row * HD + 2 * lane;
  float a0 = 0.f, a1 = 0.f;
#pragma unroll
  for (int s = 0; s < SPLIT; s++) {
    bf16x2 v = *(const bf16x2*)(Op + (size_t)s * NL * HD + oi);
    a0 += wgt[s] * (float)v[0];
    a1 += wgt[s] * (float)v[1];
  }
  bf16x2 ov = {(bf16)(a0 * inv), (bf16)(a1 * inv)};
  *(bf16x2*)(out + (size_t)l * HS + head * HD + 2 * lane) = ov;
}

// ---------------- launch ----------------
extern "C" void kernel_launch(void* const* d_in, const int* in_sizes, int n_in,
                              void* d_out, int out_size, void* d_ws, size_t ws_size,
                              hipStream_t stream) {
  const float* img = (const float*)d_in[0];
  const float* txt = (const float*)d_in[1];
  const float* vec = (const float*)d_in[2];
  const float* pe = (const float*)d_in[3];
#define PARAM(i) ((const float*)d_in[i])

  char* ws = (char*)d_ws;
  size_t off = 0;
  auto alloc = [&](size_t b) { void* p = ws + off; off += (b + 255) & ~(size_t)255; return p; };
  float* silu_s = (float*)alloc((size_t)HS * 4);
  float* mpart = (float*)alloc((size_t)8 * 2 * 12288 * 4);
  float* mod = (float*)alloc((size_t)2 * 6 * HS * 4);
  bf16* qkvT0 = (bf16*)alloc((size_t)3 * HS * HS * 2);
  bf16* qkvT1 = (bf16*)alloc((size_t)3 * HS * HS * 2);
  bf16* projT0 = (bf16*)alloc((size_t)HS * HS * 2);
  bf16* projT1 = (bf16*)alloc((size_t)HS * HS * 2);
  bf16* mlp1T0 = (bf16*)alloc((size_t)MLP_D * HS * 2);
  bf16* mlp1T1 = (bf16*)alloc((size_t)MLP_D * HS * 2);
  bf16* mlp2T0 = (bf16*)alloc((size_t)HS * MLP_D * 2);
  bf16* mlp2T1 = (bf16*)alloc((size_t)HS * MLP_D * 2);
  bf16* xm = (bf16*)alloc((size_t)LQ * HS * 2);
  bf16* y = (bf16*)alloc((size_t)LQ * 3 * HS * 2);
  bf16* qh = (bf16*)alloc((size_t)NH * LQ * HD * 2);
  bf16* kh = (bf16*)alloc((size_t)NH * LQ * HD * 2);
  bf16* vT = (bf16*)alloc((size_t)NH * HD * LQ * 2);
  bf16* attnb = (bf16*)alloc((size_t)LQ * HS * 2);
  float* x2 = (float*)alloc((size_t)LQ * HS * 4);
  bf16* xm2 = (bf16*)alloc((size_t)LQ * HS * 2);
  bf16* h = (bf16*)alloc((size_t)LQ * MLP_D * 2);
  float* ml = (float*)alloc((size_t)2 * SPLIT * NH * LQ * 4);
  bf16* Op = h;                 // attn partials alias h (dead until step 9)
  float* skpart = (float*)xm;   // split-K partials alias xm+y (42MB, dead regions)
  (void)ws_size; (void)in_sizes; (void)n_in; (void)out_size;

  const float* t_mod = mod;
  const float* i_mod = mod + 6 * HS;

  // 1) modulation vectors
  k_silu<<<HS / 256, 256, 0, stream>>>(vec, silu_s);
  k_mod_partial<<<dim3(96, 8), 256, 0, stream>>>(silu_s, PARAM(20), PARAM(4), mpart);
  k_mod_reduce<<<96, 256, 0, stream>>>(mpart, PARAM(21), PARAM(5), mod);

  // 2) weight transpose+cvt (both streams per launch)
  k_transpose_cvt2<<<dim3(3 * HS / 64, HS / 64, 2), 256, 0, stream>>>(
      PARAM(24), PARAM(8), qkvT0, qkvT1, HS, 3 * HS);
  k_transpose_cvt2<<<dim3(HS / 64, HS / 64, 2), 256, 0, stream>>>(
      PARAM(28), PARAM(12), projT0, projT1, HS, HS);
  k_transpose_cvt2<<<dim3(MLP_D / 64, HS / 64, 2), 256, 0, stream>>>(
      PARAM(32), PARAM(16), mlp1T0, mlp1T1, HS, MLP_D);
  k_transpose_cvt2<<<dim3(HS / 64, MLP_D / 64, 2), 256, 0, stream>>>(
      PARAM(34), PARAM(18), mlp2T0, mlp2T1, MLP_D, HS);

  // 3) LN1 + modulate
  k_ln_mod<<<LQ, 256, 0, stream>>>(txt, img, PARAM(22), PARAM(23), PARAM(6), PARAM(7),
                                   t_mod, i_mod, 0, 1, xm);

  // 4) qkv GEMM
  k_gemm<0><<<dim3(3 * HS / 128, LQ / 128), 256, 0, stream>>>(
      xm, HS, 3 * HS, HS, qkvT0, qkvT1, PARAM(25), PARAM(9), y, y + (size_t)LT * 3 * HS);

  // 5) RMS + RoPE ; V transpose
  k_qkv_post<<<NH * LQ / 4, 256, 0, stream>>>(y, pe, PARAM(26), PARAM(27), PARAM(10), PARAM(11),
                                              qh, kh);
  k_vtrans<<<dim3(LQ / 32, NH * 4), 256, 0, stream>>>(y, vT);

  // 6) attention (KV-split x4, 2 q-groups/wave) + combine
  k_attn<<<NH * SPLIT * 20, 256, 0, stream>>>(qh, kh, vT, Op, ml);
  k_attn_combine<<<NH * LQ / 4, 256, 0, stream>>>(Op, ml, attnb);

  // 7) proj GEMM split-K x2 + fused combine+LN2 -> x2, xm2
  k_gemm<4><<<dim3(HS / 128, LQ / 128, 2), 256, 0, stream>>>(
      attnb, HS, HS, HS / 2, projT0, projT1, nullptr, nullptr, skpart, nullptr);
  k_skcomb_ln<<<LQ, 256, 0, stream>>>(
      skpart, PARAM(29), PARAM(13), t_mod + 2 * HS, i_mod + 2 * HS, txt, img,
      PARAM(30), PARAM(31), PARAM(14), PARAM(15), t_mod, i_mod, x2, xm2);

  // 9) MLP1 + gelu
  k_gemm<2><<<dim3(MLP_D / 128, LQ / 128), 256, 0, stream>>>(
      xm2, HS, MLP_D, HS, mlp1T0, mlp1T1, PARAM(33), PARAM(17), h, h + (size_t)LT * MLP_D);

  // 10) MLP2 split-K x2 + combine -> d_out (img first)
  float* out_img = (float*)d_out;
  float* out_txt = (float*)d_out + (size_t)LI * HS;
  k_gemm<4><<<dim3(HS / 128, LQ / 128, 2), 256, 0, stream>>>(
      h, MLP_D, HS, MLP_D / 2, mlp2T0, mlp2T1, nullptr, nullptr, skpart, nullptr);
  k_skcomb<2><<<LQ * HS / 4 / 256, 256, 0, stream>>>(
      skpart, HS, PARAM(35), PARAM(19), t_mod + 5 * HS, i_mod + 5 * HS, x2,
      x2 + (size_t)LT * HS, out_txt, out_img);
}